// Round 9
// baseline (486.063 us; speedup 1.0000x reference)
//
#include <hip/hip_runtime.h>
#include <hip/hip_fp16.h>

#define D 128
#define EDGE_IN 258
#define TI 64  // actors per block (R8: 32 -> 64 halves per-wave weight re-fetch from L2)

__device__ __forceinline__ float rl_f(float v, int j) {
  return __int_as_float(__builtin_amdgcn_readlane(__float_as_int(v), j));
}
__device__ __forceinline__ int rl_i(int v, int j) {
  return __builtin_amdgcn_readlane(v, j);
}
__device__ __forceinline__ float dot4(float4 a, float4 b) {
  return a.x * b.x + a.y * b.y + a.z * b.z + a.w * b.w;
}

// ---------------- CSR build ----------------
__global__ void zero_int(int* __restrict__ p, int n) {
  int i = blockIdx.x * blockDim.x + threadIdx.x;
  if (i < n) p[i] = 0;
}

__global__ void hist_kernel(const int* __restrict__ dst, int* __restrict__ deg, int ne) {
  int e = blockIdx.x * blockDim.x + threadIdx.x;
  if (e < ne) atomicAdd(&deg[dst[e]], 1);
}

// hierarchical scan: stage 1 — per-block (1024-elem chunk) sums
__global__ __launch_bounds__(256) void scan_part(const int* __restrict__ deg,
                                                 int* __restrict__ bsum, int n) {
  __shared__ int red[256];
  int b = blockIdx.x, tid = threadIdx.x;
  int base = b * 1024 + tid * 4;
  int s = 0;
#pragma unroll
  for (int j = 0; j < 4; j++) { int idx = base + j; if (idx < n) s += deg[idx]; }
  red[tid] = s;
  __syncthreads();
  for (int off = 128; off; off >>= 1) {
    if (tid < off) red[tid] += red[tid + off];
    __syncthreads();
  }
  if (tid == 0) bsum[b] = red[0];
}

// stage 2 — scan the block sums (nb <= 256) in one small block
__global__ __launch_bounds__(256) void scan_bsums(int* __restrict__ bsum, int nb) {
  __shared__ int part[256];
  int tid = threadIdx.x;
  int v = (tid < nb) ? bsum[tid] : 0;
  part[tid] = v;
  __syncthreads();
  for (int off = 1; off < 256; off <<= 1) {
    int t = (tid >= off) ? part[tid - off] : 0;
    __syncthreads();
    part[tid] += t;
    __syncthreads();
  }
  if (tid < nb) bsum[tid] = (tid == 0) ? 0 : part[tid - 1];  // exclusive
}

// stage 3 — per-block rescan + global offset; writes offs and cur
__global__ __launch_bounds__(256) void scan_final(const int* __restrict__ deg,
                                                  const int* __restrict__ bsumex,
                                                  int* __restrict__ offs,
                                                  int* __restrict__ cur, int n, int ne) {
  __shared__ int part[256];
  int b = blockIdx.x, tid = threadIdx.x;
  int base = b * 1024 + tid * 4;
  int v[4];
  int s = 0;
#pragma unroll
  for (int j = 0; j < 4; j++) {
    int idx = base + j;
    v[j] = (idx < n) ? deg[idx] : 0;
    s += v[j];
  }
  part[tid] = s;
  __syncthreads();
  for (int off = 1; off < 256; off <<= 1) {
    int t = (tid >= off) ? part[tid - off] : 0;
    __syncthreads();
    part[tid] += t;
    __syncthreads();
  }
  int run = bsumex[b] + ((tid == 0) ? 0 : part[tid - 1]);
#pragma unroll
  for (int j = 0; j < 4; j++) {
    int idx = base + j;
    if (idx < n) { offs[idx] = run; cur[idx] = run; run += v[j]; }
  }
  if (b == 0 && tid == 0) offs[n] = ne;
}

// pre-gather edge metadata into CSR slot order: meta[p] = {src, rx, ry, -}
__global__ void scatter_kernel(const int* __restrict__ dst, const int* __restrict__ srcIdx,
                               const float2* __restrict__ rel, int* __restrict__ cur,
                               float4* __restrict__ meta, int ne) {
  int e = blockIdx.x * blockDim.x + threadIdx.x;
  if (e < ne) {
    int p = atomicAdd(&cur[dst[e]], 1);
    float2 r = rel[e];
    meta[p] = make_float4(__int_as_float(srcIdx[e]), r.x, r.y, 0.f);
  }
}

// ---------------- weight prep ----------------
// WT (float4 view): [L][2(src,dst)][32(k4)][128(d)], float4 holds k..k+3
// Wrel: [L][2][128]   WattA: [L][2][128] (16B-aligned repack of W_att)
__global__ void transpose_kernel(const float* __restrict__ W_emb,
                                 const float* __restrict__ W_att,
                                 float* __restrict__ WT, float* __restrict__ Wrel,
                                 float* __restrict__ WattA) {
  int d = threadIdx.x;      // 0..127
  int k = blockIdx.x;       // 0..127
  int part = blockIdx.y;    // 0,1 = src/dst emb ; 2 = rel emb cols ; 3,4 = att src/dst
  int l = blockIdx.z;
  if (part < 2) {
    int off = part ? 130 : 0;
    int mat = l * 2 + part;
    WT[((mat * 32 + (k >> 2)) * 128 + d) * 4 + (k & 3)] =
        W_emb[(size_t)(l * D + d) * EDGE_IN + off + k];
  } else if (part == 2) {
    if (k < 2) Wrel[(l * 2 + k) * 128 + d] = W_emb[(size_t)(l * D + d) * EDGE_IN + 128 + k];
  } else if (k == 0) {
    int off = (part == 3) ? 0 : 130;
    WattA[(l * 2 + (part - 3)) * 128 + d] = W_att[(size_t)l * EDGE_IN + off + d];
  }
}

// ---------------- fused per-actor projections + attention dots ----------------
// 8 actors x 4 STRIDED dims per thread (d = dg+32j, dg=tid&31):
//  - weight loads: lanes 0..31 read 32 consecutive float4 (512B) -> coalesced,
//    upper half-wave broadcasts. Per-wave weight stream = 256KB/32 iters;
//    TI=64 halves total wave count -> L2 weight traffic 1.6GB -> 0.8GB (~23us),
//    matching the ~21us FMA floor. (R8: TI=32 was L2-bound at 77us, VALU 51%.)
//  - feat LDS reads: 2-address broadcast, conflict-free.
__global__ __launch_bounds__(256) void proj_kernel(const float* __restrict__ feat,
                                                   const float4* __restrict__ WT,
                                                   const float* __restrict__ WattA,
                                                   __half* __restrict__ Ps16,
                                                   float* __restrict__ Pd,
                                                   float* __restrict__ a_s,
                                                   float* __restrict__ a_d, int n, int l) {
  __shared__ float lf[TI][D];  // 32 KB
  int i0 = blockIdx.x * TI;
  int tid = threadIdx.x;
  for (int t = tid; t < TI * D / 4; t += 256) {
    int fi = t >> 5;
    int gi = i0 + fi;
    float4 v = (gi < n) ? ((const float4*)feat)[(size_t)gi * (D / 4) + (t & 31)]
                        : make_float4(0.f, 0.f, 0.f, 0.f);
    ((float4*)&lf[0][0])[t] = v;
  }
  __syncthreads();
  int dg = tid & 31;  // dims dg, dg+32, dg+64, dg+96
  int ag = tid >> 5;  // actors 8ag..8ag+7
  const float4* Ws = WT + (size_t)(l * 2 + 0) * 32 * 128;
  const float4* Wd = WT + (size_t)(l * 2 + 1) * 32 * 128;
  float accs[8][4], accd[8][4];  // [actor][dim j]
#pragma unroll
  for (int a = 0; a < 8; a++)
#pragma unroll
    for (int j = 0; j < 4; j++) { accs[a][j] = 0.f; accd[a][j] = 0.f; }

  for (int k4 = 0; k4 < 32; k4++) {
    float4 fa[8], wsv[4], wdv[4];
#pragma unroll
    for (int j = 0; j < 4; j++) {
      wsv[j] = Ws[k4 * 128 + dg + 32 * j];  // coalesced: 32 consecutive float4
      wdv[j] = Wd[k4 * 128 + dg + 32 * j];
    }
#pragma unroll
    for (int a = 0; a < 8; a++) fa[a] = *(const float4*)&lf[8 * ag + a][k4 * 4];
#pragma unroll
    for (int a = 0; a < 8; a++)
#pragma unroll
      for (int j = 0; j < 4; j++) {
        accs[a][j] += dot4(fa[a], wsv[j]);
        accd[a][j] += dot4(fa[a], wdv[j]);
      }
  }

  // attention dots: each dim-group lane covers k-chunk k4==dg, then reduce over 32 lanes
  float sa[8], ta[8];
  {
    float4 was = *(const float4*)&WattA[(size_t)(l * 2 + 0) * 128 + 4 * dg];
    float4 wat = *(const float4*)&WattA[(size_t)(l * 2 + 1) * 128 + 4 * dg];
#pragma unroll
    for (int a = 0; a < 8; a++) {
      float4 f = *(const float4*)&lf[8 * ag + a][4 * dg];
      sa[a] = dot4(f, was);
      ta[a] = dot4(f, wat);
    }
#pragma unroll
    for (int o = 1; o < 32; o <<= 1) {
#pragma unroll
      for (int a = 0; a < 8; a++) {
        sa[a] += __shfl_xor(sa[a], o, 64);
        ta[a] += __shfl_xor(ta[a], o, 64);
      }
    }
  }

#pragma unroll
  for (int a = 0; a < 8; a++) {
    int gi = i0 + 8 * ag + a;
    if (gi < n) {
#pragma unroll
      for (int j = 0; j < 4; j++) {
        Ps16[(size_t)gi * D + dg + 32 * j] = __float2half(accs[a][j]);
        Pd[(size_t)gi * D + dg + 32 * j] = accd[a][j];
      }
      if (dg == 0) { a_s[gi] = sa[a]; a_d[gi] = ta[a]; }
    }
  }
}

// ---------------- edge pass: one wave per dst ----------------
// Phase A: lane-parallel scores, wave-reduced softmax.
// Phase B: 8-deep independent Ps gathers.
__global__ __launch_bounds__(256) void edge_kernel(
    const __half2* __restrict__ Ps, const float* __restrict__ Pd,
    const float* __restrict__ a_s, const float* __restrict__ a_d,
    const float4* __restrict__ meta, const int* __restrict__ offs,
    const float* __restrict__ Wrel, const float* __restrict__ W_att,
    float* __restrict__ out, int n, int l) {
  int wid = (blockIdx.x * blockDim.x + threadIdx.x) >> 6;
  if (wid >= n) return;
  int lane = threadIdx.x & 63;
  int d0 = 2 * lane;
  const float2 wc0 = *(const float2*)&Wrel[(l * 2 + 0) * 128 + d0];
  const float2 wc1 = *(const float2*)&Wrel[(l * 2 + 1) * 128 + d0];
  float wax = W_att[(size_t)l * EDGE_IN + 128];
  float way = W_att[(size_t)l * EDGE_IN + 129];
  float ad = a_d[wid];
  int p0 = offs[wid], p1 = offs[wid + 1];
  float m = -1e30f, lsum = 0.f;
  float accx = 0.f, accy = 0.f;
  for (int c0 = p0; c0 < p1; c0 += 64) {
    int cn = min(64, p1 - c0);
    int si = 0;
    float rx = 0.f, ry = 0.f, s = -1e30f;
    if (lane < cn) {
      float4 mt = meta[c0 + lane];
      si = __float_as_int(mt.x);
      rx = mt.y;
      ry = mt.z;
      float sc = a_s[si] + ad + rx * wax + ry * way;
      s = (sc > 0.f) ? sc : 0.2f * sc;
    }
    float cm = s;
#pragma unroll
    for (int o = 32; o; o >>= 1) cm = fmaxf(cm, __shfl_xor(cm, o, 64));
    float mnew = fmaxf(m, cm);
    float corrOld = __expf(m - mnew);
    float w = (lane < cn) ? __expf(s - mnew) : 0.f;
    float csum = w;
#pragma unroll
    for (int o = 32; o; o >>= 1) csum += __shfl_xor(csum, o, 64);
    lsum = lsum * corrOld + csum;
    accx *= corrOld;
    accy *= corrOld;
    m = mnew;
    int j = 0;
    for (; j + 8 <= cn; j += 8) {
      float2 f[8];
      float wj[8], xj[8], yj[8];
#pragma unroll
      for (int q = 0; q < 8; q++) {
        int sj = rl_i(si, j + q);
        wj[q] = rl_f(w, j + q);
        xj[q] = rl_f(rx, j + q);
        yj[q] = rl_f(ry, j + q);
        f[q] = __half22float2(Ps[(size_t)sj * 64 + lane]);
      }
#pragma unroll
      for (int q = 0; q < 8; q++) {
        accx += wj[q] * (f[q].x + xj[q] * wc0.x + yj[q] * wc1.x);
        accy += wj[q] * (f[q].y + xj[q] * wc0.y + yj[q] * wc1.y);
      }
    }
    if (j < cn) {
      float2 f[8];
      float wj[8], xj[8], yj[8];
      int r = cn - j;  // 1..7
#pragma unroll
      for (int q = 0; q < 8; q++) {
        if (q < r) {
          int sj = rl_i(si, j + q);
          wj[q] = rl_f(w, j + q);
          xj[q] = rl_f(rx, j + q);
          yj[q] = rl_f(ry, j + q);
          f[q] = __half22float2(Ps[(size_t)sj * 64 + lane]);
        }
      }
#pragma unroll
      for (int q = 0; q < 8; q++) {
        if (q < r) {
          accx += wj[q] * (f[q].x + xj[q] * wc0.x + yj[q] * wc1.x);
          accy += wj[q] * (f[q].y + xj[q] * wc0.y + yj[q] * wc1.y);
        }
      }
    }
  }
  float2 o2 = make_float2(0.f, 0.f);
  if (p1 > p0) {
    float inv = 1.0f / lsum;
    float2 pd = *(const float2*)&Pd[(size_t)wid * D + d0];
    o2.x = fmaxf(accx * inv + pd.x, 0.f);
    o2.y = fmaxf(accy * inv + pd.y, 0.f);
  }
  *(float2*)&out[(size_t)wid * D + d0] = o2;
}

extern "C" void kernel_launch(void* const* d_in, const int* in_sizes, int n_in,
                              void* d_out, int out_size, void* d_ws, size_t ws_size,
                              hipStream_t stream) {
  const float* actor = (const float*)d_in[0];
  const float* rel   = (const float*)d_in[1];
  const float* W_att = (const float*)d_in[2];
  const float* W_emb = (const float*)d_in[3];
  const int* srcIdx  = (const int*)d_in[4];
  const int* dstIdx  = (const int*)d_in[5];
  int n  = in_sizes[0] / D;          // 50000
  int ne = in_sizes[4];              // 800000
  int Lnum = in_sizes[2] / EDGE_IN;  // 2
  float* fout_last = (float*)d_out;

  // workspace carve-up (meta first for 16B alignment)
  float* ws = (float*)d_ws;
  size_t o = 0;
  float4* meta = (float4*)ws; o += 4 * (size_t)ne;
  float* WT  = ws + o; o += (size_t)Lnum * 2 * 128 * 128;
  float* Wre = ws + o; o += (size_t)Lnum * 2 * 128;
  float* WattA = ws + o; o += (size_t)Lnum * 2 * 128;
  float* Pd  = ws + o; o += (size_t)n * D;
  float* a_s = ws + o; o += (size_t)n + 64;
  float* a_d = ws + o; o += (size_t)n + 64;
  __half* Ps16 = (__half*)(ws + o); o += (size_t)n * D / 2;
  int* ibuf = (int*)(ws + o);
  size_t io = 0;
  int* deg  = ibuf + io; io += n + 64;
  int* offs = ibuf + io; io += n + 64;
  int* cur  = ibuf + io; io += n + 64;
  int* bsum = ibuf + io; io += 256;

  int nb = (n + 1023) / 1024;  // chunk-blocks for the scan

  // --- CSR by dst with pre-gathered per-edge metadata ---
  zero_int<<<(n + 255) / 256, 256, 0, stream>>>(deg, n);
  hist_kernel<<<(ne + 255) / 256, 256, 0, stream>>>(dstIdx, deg, ne);
  scan_part<<<nb, 256, 0, stream>>>(deg, bsum, n);
  scan_bsums<<<1, 256, 0, stream>>>(bsum, nb);
  scan_final<<<nb, 256, 0, stream>>>(deg, bsum, offs, cur, n, ne);
  scatter_kernel<<<(ne + 255) / 256, 256, 0, stream>>>(dstIdx, srcIdx, (const float2*)rel,
                                                       cur, meta, ne);
  transpose_kernel<<<dim3(128, 5, Lnum), 128, 0, stream>>>(W_emb, W_att, WT, Wre, WattA);

  // --- layers; d_out doubles as the intermediate feature buffer ---
  const float* fin = actor;
  for (int l = 0; l < Lnum; l++) {
    proj_kernel<<<(n + TI - 1) / TI, 256, 0, stream>>>(fin, (const float4*)WT, WattA,
                                                       Ps16, Pd, a_s, a_d, n, l);
    edge_kernel<<<(n + 3) / 4, 256, 0, stream>>>((const __half2*)Ps16, Pd, a_s, a_d, meta,
                                                 offs, Wre, W_att, fout_last, n, l);
    fin = fout_last;
  }
}

// Round 10
// 421.657 us; speedup vs baseline: 1.1527x; 1.1527x over previous
//
#include <hip/hip_runtime.h>
#include <hip/hip_fp16.h>

#define D 128
#define EDGE_IN 258
#define TI 32

__device__ __forceinline__ float rl_f(float v, int j) {
  return __int_as_float(__builtin_amdgcn_readlane(__float_as_int(v), j));
}
__device__ __forceinline__ int rl_i(int v, int j) {
  return __builtin_amdgcn_readlane(v, j);
}
__device__ __forceinline__ float dot4(float4 a, float4 b) {
  return a.x * b.x + a.y * b.y + a.z * b.z + a.w * b.w;
}

// ---------------- CSR build ----------------
__global__ void zero_int(int* __restrict__ p, int n) {
  int i = blockIdx.x * blockDim.x + threadIdx.x;
  if (i < n) p[i] = 0;
}

__global__ void hist_kernel(const int* __restrict__ dst, int* __restrict__ deg, int ne) {
  int e = blockIdx.x * blockDim.x + threadIdx.x;
  if (e < ne) atomicAdd(&deg[dst[e]], 1);
}

// hierarchical scan: stage 1 — per-block (1024-elem chunk) sums
__global__ __launch_bounds__(256) void scan_part(const int* __restrict__ deg,
                                                 int* __restrict__ bsum, int n) {
  __shared__ int red[256];
  int b = blockIdx.x, tid = threadIdx.x;
  int base = b * 1024 + tid * 4;
  int s = 0;
#pragma unroll
  for (int j = 0; j < 4; j++) { int idx = base + j; if (idx < n) s += deg[idx]; }
  red[tid] = s;
  __syncthreads();
  for (int off = 128; off; off >>= 1) {
    if (tid < off) red[tid] += red[tid + off];
    __syncthreads();
  }
  if (tid == 0) bsum[b] = red[0];
}

// stage 2 — scan the block sums (nb <= 256) in one small block
__global__ __launch_bounds__(256) void scan_bsums(int* __restrict__ bsum, int nb) {
  __shared__ int part[256];
  int tid = threadIdx.x;
  int v = (tid < nb) ? bsum[tid] : 0;
  part[tid] = v;
  __syncthreads();
  for (int off = 1; off < 256; off <<= 1) {
    int t = (tid >= off) ? part[tid - off] : 0;
    __syncthreads();
    part[tid] += t;
    __syncthreads();
  }
  if (tid < nb) bsum[tid] = (tid == 0) ? 0 : part[tid - 1];  // exclusive
}

// stage 3 — per-block rescan + global offset; writes offs and cur
__global__ __launch_bounds__(256) void scan_final(const int* __restrict__ deg,
                                                  const int* __restrict__ bsumex,
                                                  int* __restrict__ offs,
                                                  int* __restrict__ cur, int n, int ne) {
  __shared__ int part[256];
  int b = blockIdx.x, tid = threadIdx.x;
  int base = b * 1024 + tid * 4;
  int v[4];
  int s = 0;
#pragma unroll
  for (int j = 0; j < 4; j++) {
    int idx = base + j;
    v[j] = (idx < n) ? deg[idx] : 0;
    s += v[j];
  }
  part[tid] = s;
  __syncthreads();
  for (int off = 1; off < 256; off <<= 1) {
    int t = (tid >= off) ? part[tid - off] : 0;
    __syncthreads();
    part[tid] += t;
    __syncthreads();
  }
  int run = bsumex[b] + ((tid == 0) ? 0 : part[tid - 1]);
#pragma unroll
  for (int j = 0; j < 4; j++) {
    int idx = base + j;
    if (idx < n) { offs[idx] = run; cur[idx] = run; run += v[j]; }
  }
  if (b == 0 && tid == 0) offs[n] = ne;
}

// pre-gather edge metadata into CSR slot order: meta[p] = {src, rx, ry, -}
__global__ void scatter_kernel(const int* __restrict__ dst, const int* __restrict__ srcIdx,
                               const float2* __restrict__ rel, int* __restrict__ cur,
                               float4* __restrict__ meta, int ne) {
  int e = blockIdx.x * blockDim.x + threadIdx.x;
  if (e < ne) {
    int p = atomicAdd(&cur[dst[e]], 1);
    float2 r = rel[e];
    meta[p] = make_float4(__int_as_float(srcIdx[e]), r.x, r.y, 0.f);
  }
}

// ---------------- weight prep ----------------
// WT (float4 view): [L][2(src,dst)][32(k4)][128(d)], float4 holds k..k+3
// Wrel: [L][2][128]   WattA: [L][2][128] (16B-aligned repack of W_att)
__global__ void transpose_kernel(const float* __restrict__ W_emb,
                                 const float* __restrict__ W_att,
                                 float* __restrict__ WT, float* __restrict__ Wrel,
                                 float* __restrict__ WattA) {
  int d = threadIdx.x;      // 0..127
  int k = blockIdx.x;       // 0..127
  int part = blockIdx.y;    // 0,1 = src/dst emb ; 2 = rel emb cols ; 3,4 = att src/dst
  int l = blockIdx.z;
  if (part < 2) {
    int off = part ? 130 : 0;
    int mat = l * 2 + part;
    WT[((mat * 32 + (k >> 2)) * 128 + d) * 4 + (k & 3)] =
        W_emb[(size_t)(l * D + d) * EDGE_IN + off + k];
  } else if (part == 2) {
    if (k < 2) Wrel[(l * 2 + k) * 128 + d] = W_emb[(size_t)(l * D + d) * EDGE_IN + 128 + k];
  } else if (k == 0) {
    int off = (part == 3) ? 0 : 130;
    WattA[(l * 2 + (part - 3)) * 128 + d] = W_att[(size_t)l * EDGE_IN + off + d];
  }
}

// ---------------- per-actor projection + attention dot, ONE matrix per block ----
// blockIdx.y: 0 = src matrix (-> Ps16 fp16, a_s), 1 = dst matrix (-> Pd fp32, a_d).
// R9 lesson: TI=64 halved the grid to 3 blocks/CU -> occupancy 17% -> regression.
// This split keeps TI=32 (12 blocks/CU) and halves per-thread work instead:
// acc 4x4 only (~45 VGPR), 2048 FMA/thread -> 2x the waves to hide the L2
// weight stream; 4 waves/block share each 4KB k4-window of W in L1.
__global__ __launch_bounds__(256) void proj_kernel(const float* __restrict__ feat,
                                                   const float4* __restrict__ WT,
                                                   const float* __restrict__ WattA,
                                                   __half* __restrict__ Ps16,
                                                   float* __restrict__ Pd,
                                                   float* __restrict__ a_s,
                                                   float* __restrict__ a_d, int n, int l) {
  __shared__ float lf[TI][D];  // 16 KB
  int i0 = blockIdx.x * TI;
  int part = blockIdx.y;  // 0=src, 1=dst (wave-uniform)
  int tid = threadIdx.x;
  for (int t = tid; t < TI * D / 4; t += 256) {
    int fi = t >> 5;
    int gi = i0 + fi;
    float4 v = (gi < n) ? ((const float4*)feat)[(size_t)gi * (D / 4) + (t & 31)]
                        : make_float4(0.f, 0.f, 0.f, 0.f);
    ((float4*)&lf[0][0])[t] = v;
  }
  __syncthreads();
  int dg = tid & 31;  // dims dg, dg+32, dg+64, dg+96
  int ag = tid >> 5;  // actors 4ag..4ag+3
  const float4* W = WT + (size_t)(l * 2 + part) * 32 * 128;
  float acc[4][4];  // [actor][dim j]
#pragma unroll
  for (int a = 0; a < 4; a++)
#pragma unroll
    for (int j = 0; j < 4; j++) acc[a][j] = 0.f;

  for (int k4 = 0; k4 < 32; k4++) {
    float4 fa[4], wv[4];
#pragma unroll
    for (int j = 0; j < 4; j++) wv[j] = W[k4 * 128 + dg + 32 * j];  // 512B contiguous/halfwave
#pragma unroll
    for (int a = 0; a < 4; a++) fa[a] = *(const float4*)&lf[4 * ag + a][k4 * 4];
#pragma unroll
    for (int a = 0; a < 4; a++)
#pragma unroll
      for (int j = 0; j < 4; j++) acc[a][j] += dot4(fa[a], wv[j]);
  }

  // attention dot for this part: lane dg covers k-chunk 4dg..4dg+3, reduce over 32 lanes
  float sa[4];
  {
    float4 wa = *(const float4*)&WattA[(size_t)(l * 2 + part) * 128 + 4 * dg];
#pragma unroll
    for (int a = 0; a < 4; a++) sa[a] = dot4(*(const float4*)&lf[4 * ag + a][4 * dg], wa);
#pragma unroll
    for (int o = 1; o < 32; o <<= 1) {
#pragma unroll
      for (int a = 0; a < 4; a++) sa[a] += __shfl_xor(sa[a], o, 64);
    }
  }

  if (part == 0) {
#pragma unroll
    for (int a = 0; a < 4; a++) {
      int gi = i0 + 4 * ag + a;
      if (gi < n) {
#pragma unroll
        for (int j = 0; j < 4; j++)
          Ps16[(size_t)gi * D + dg + 32 * j] = __float2half(acc[a][j]);
        if (dg == 0) a_s[gi] = sa[a];
      }
    }
  } else {
#pragma unroll
    for (int a = 0; a < 4; a++) {
      int gi = i0 + 4 * ag + a;
      if (gi < n) {
#pragma unroll
        for (int j = 0; j < 4; j++)
          Pd[(size_t)gi * D + dg + 32 * j] = acc[a][j];
        if (dg == 0) a_d[gi] = sa[a];
      }
    }
  }
}

// ---------------- edge pass: one wave per dst ----------------
// Phase A: lane-parallel scores, wave-reduced softmax.
// Phase B: 8-deep independent Ps gathers.
__global__ __launch_bounds__(256) void edge_kernel(
    const __half2* __restrict__ Ps, const float* __restrict__ Pd,
    const float* __restrict__ a_s, const float* __restrict__ a_d,
    const float4* __restrict__ meta, const int* __restrict__ offs,
    const float* __restrict__ Wrel, const float* __restrict__ W_att,
    float* __restrict__ out, int n, int l) {
  int wid = (blockIdx.x * blockDim.x + threadIdx.x) >> 6;
  if (wid >= n) return;
  int lane = threadIdx.x & 63;
  int d0 = 2 * lane;
  const float2 wc0 = *(const float2*)&Wrel[(l * 2 + 0) * 128 + d0];
  const float2 wc1 = *(const float2*)&Wrel[(l * 2 + 1) * 128 + d0];
  float wax = W_att[(size_t)l * EDGE_IN + 128];
  float way = W_att[(size_t)l * EDGE_IN + 129];
  float ad = a_d[wid];
  int p0 = offs[wid], p1 = offs[wid + 1];
  float m = -1e30f, lsum = 0.f;
  float accx = 0.f, accy = 0.f;
  for (int c0 = p0; c0 < p1; c0 += 64) {
    int cn = min(64, p1 - c0);
    int si = 0;
    float rx = 0.f, ry = 0.f, s = -1e30f;
    if (lane < cn) {
      float4 mt = meta[c0 + lane];
      si = __float_as_int(mt.x);
      rx = mt.y;
      ry = mt.z;
      float sc = a_s[si] + ad + rx * wax + ry * way;
      s = (sc > 0.f) ? sc : 0.2f * sc;
    }
    float cm = s;
#pragma unroll
    for (int o = 32; o; o >>= 1) cm = fmaxf(cm, __shfl_xor(cm, o, 64));
    float mnew = fmaxf(m, cm);
    float corrOld = __expf(m - mnew);
    float w = (lane < cn) ? __expf(s - mnew) : 0.f;
    float csum = w;
#pragma unroll
    for (int o = 32; o; o >>= 1) csum += __shfl_xor(csum, o, 64);
    lsum = lsum * corrOld + csum;
    accx *= corrOld;
    accy *= corrOld;
    m = mnew;
    int j = 0;
    for (; j + 8 <= cn; j += 8) {
      float2 f[8];
      float wj[8], xj[8], yj[8];
#pragma unroll
      for (int q = 0; q < 8; q++) {
        int sj = rl_i(si, j + q);
        wj[q] = rl_f(w, j + q);
        xj[q] = rl_f(rx, j + q);
        yj[q] = rl_f(ry, j + q);
        f[q] = __half22float2(Ps[(size_t)sj * 64 + lane]);
      }
#pragma unroll
      for (int q = 0; q < 8; q++) {
        accx += wj[q] * (f[q].x + xj[q] * wc0.x + yj[q] * wc1.x);
        accy += wj[q] * (f[q].y + xj[q] * wc0.y + yj[q] * wc1.y);
      }
    }
    if (j < cn) {
      float2 f[8];
      float wj[8], xj[8], yj[8];
      int r = cn - j;  // 1..7
#pragma unroll
      for (int q = 0; q < 8; q++) {
        if (q < r) {
          int sj = rl_i(si, j + q);
          wj[q] = rl_f(w, j + q);
          xj[q] = rl_f(rx, j + q);
          yj[q] = rl_f(ry, j + q);
          f[q] = __half22float2(Ps[(size_t)sj * 64 + lane]);
        }
      }
#pragma unroll
      for (int q = 0; q < 8; q++) {
        if (q < r) {
          accx += wj[q] * (f[q].x + xj[q] * wc0.x + yj[q] * wc1.x);
          accy += wj[q] * (f[q].y + xj[q] * wc0.y + yj[q] * wc1.y);
        }
      }
    }
  }
  float2 o2 = make_float2(0.f, 0.f);
  if (p1 > p0) {
    float inv = 1.0f / lsum;
    float2 pd = *(const float2*)&Pd[(size_t)wid * D + d0];
    o2.x = fmaxf(accx * inv + pd.x, 0.f);
    o2.y = fmaxf(accy * inv + pd.y, 0.f);
  }
  *(float2*)&out[(size_t)wid * D + d0] = o2;
}

extern "C" void kernel_launch(void* const* d_in, const int* in_sizes, int n_in,
                              void* d_out, int out_size, void* d_ws, size_t ws_size,
                              hipStream_t stream) {
  const float* actor = (const float*)d_in[0];
  const float* rel   = (const float*)d_in[1];
  const float* W_att = (const float*)d_in[2];
  const float* W_emb = (const float*)d_in[3];
  const int* srcIdx  = (const int*)d_in[4];
  const int* dstIdx  = (const int*)d_in[5];
  int n  = in_sizes[0] / D;          // 50000
  int ne = in_sizes[4];              // 800000
  int Lnum = in_sizes[2] / EDGE_IN;  // 2
  float* fout_last = (float*)d_out;

  // workspace carve-up (meta first for 16B alignment)
  float* ws = (float*)d_ws;
  size_t o = 0;
  float4* meta = (float4*)ws; o += 4 * (size_t)ne;
  float* WT  = ws + o; o += (size_t)Lnum * 2 * 128 * 128;
  float* Wre = ws + o; o += (size_t)Lnum * 2 * 128;
  float* WattA = ws + o; o += (size_t)Lnum * 2 * 128;
  float* Pd  = ws + o; o += (size_t)n * D;
  float* a_s = ws + o; o += (size_t)n + 64;
  float* a_d = ws + o; o += (size_t)n + 64;
  __half* Ps16 = (__half*)(ws + o); o += (size_t)n * D / 2;
  int* ibuf = (int*)(ws + o);
  size_t io = 0;
  int* deg  = ibuf + io; io += n + 64;
  int* offs = ibuf + io; io += n + 64;
  int* cur  = ibuf + io; io += n + 64;
  int* bsum = ibuf + io; io += 256;

  int nb = (n + 1023) / 1024;  // chunk-blocks for the scan

  // --- CSR by dst with pre-gathered per-edge metadata ---
  zero_int<<<(n + 255) / 256, 256, 0, stream>>>(deg, n);
  hist_kernel<<<(ne + 255) / 256, 256, 0, stream>>>(dstIdx, deg, ne);
  scan_part<<<nb, 256, 0, stream>>>(deg, bsum, n);
  scan_bsums<<<1, 256, 0, stream>>>(bsum, nb);
  scan_final<<<nb, 256, 0, stream>>>(deg, bsum, offs, cur, n, ne);
  scatter_kernel<<<(ne + 255) / 256, 256, 0, stream>>>(dstIdx, srcIdx, (const float2*)rel,
                                                       cur, meta, ne);
  transpose_kernel<<<dim3(128, 5, Lnum), 128, 0, stream>>>(W_emb, W_att, WT, Wre, WattA);

  // --- layers; d_out doubles as the intermediate feature buffer ---
  const float* fin = actor;
  for (int l = 0; l < Lnum; l++) {
    proj_kernel<<<dim3((n + TI - 1) / TI, 2), 256, 0, stream>>>(
        fin, (const float4*)WT, WattA, Ps16, Pd, a_s, a_d, n, l);
    edge_kernel<<<(n + 3) / 4, 256, 0, stream>>>((const __half2*)Ps16, Pd, a_s, a_d, meta,
                                                 offs, Wre, W_att, fout_last, n, l);
    fin = fout_last;
  }
}

// Round 11
// 367.598 us; speedup vs baseline: 1.3223x; 1.1471x over previous
//
#include <hip/hip_runtime.h>
#include <hip/hip_fp16.h>

#define D 128
#define EDGE_IN 258

typedef __attribute__((ext_vector_type(8))) short bf16x8;
typedef __attribute__((ext_vector_type(4))) float f32x4;

__device__ __forceinline__ float rl_f(float v, int j) {
  return __int_as_float(__builtin_amdgcn_readlane(__float_as_int(v), j));
}
__device__ __forceinline__ int rl_i(int v, int j) {
  return __builtin_amdgcn_readlane(v, j);
}
__device__ __forceinline__ ushort f32_to_bf16(float f) {
  unsigned u = __float_as_uint(f);
  unsigned r = (u + 0x7FFFu + ((u >> 16) & 1u)) >> 16;  // RNE
  return (ushort)r;
}
__device__ __forceinline__ float bf16_to_f32(ushort h) {
  return __uint_as_float(((unsigned)h) << 16);
}

// ---------------- CSR build ----------------
__global__ void zero_int(int* __restrict__ p, int n) {
  int i = blockIdx.x * blockDim.x + threadIdx.x;
  if (i < n) p[i] = 0;
}

__global__ void hist_kernel(const int* __restrict__ dst, int* __restrict__ deg, int ne) {
  int e = blockIdx.x * blockDim.x + threadIdx.x;
  if (e < ne) atomicAdd(&deg[dst[e]], 1);
}

__global__ __launch_bounds__(256) void scan_part(const int* __restrict__ deg,
                                                 int* __restrict__ bsum, int n) {
  __shared__ int red[256];
  int b = blockIdx.x, tid = threadIdx.x;
  int base = b * 1024 + tid * 4;
  int s = 0;
#pragma unroll
  for (int j = 0; j < 4; j++) { int idx = base + j; if (idx < n) s += deg[idx]; }
  red[tid] = s;
  __syncthreads();
  for (int off = 128; off; off >>= 1) {
    if (tid < off) red[tid] += red[tid + off];
    __syncthreads();
  }
  if (tid == 0) bsum[b] = red[0];
}

__global__ __launch_bounds__(256) void scan_bsums(int* __restrict__ bsum, int nb) {
  __shared__ int part[256];
  int tid = threadIdx.x;
  int v = (tid < nb) ? bsum[tid] : 0;
  part[tid] = v;
  __syncthreads();
  for (int off = 1; off < 256; off <<= 1) {
    int t = (tid >= off) ? part[tid - off] : 0;
    __syncthreads();
    part[tid] += t;
    __syncthreads();
  }
  if (tid < nb) bsum[tid] = (tid == 0) ? 0 : part[tid - 1];  // exclusive
}

__global__ __launch_bounds__(256) void scan_final(const int* __restrict__ deg,
                                                  const int* __restrict__ bsumex,
                                                  int* __restrict__ offs,
                                                  int* __restrict__ cur, int n, int ne) {
  __shared__ int part[256];
  int b = blockIdx.x, tid = threadIdx.x;
  int base = b * 1024 + tid * 4;
  int v[4];
  int s = 0;
#pragma unroll
  for (int j = 0; j < 4; j++) {
    int idx = base + j;
    v[j] = (idx < n) ? deg[idx] : 0;
    s += v[j];
  }
  part[tid] = s;
  __syncthreads();
  for (int off = 1; off < 256; off <<= 1) {
    int t = (tid >= off) ? part[tid - off] : 0;
    __syncthreads();
    part[tid] += t;
    __syncthreads();
  }
  int run = bsumex[b] + ((tid == 0) ? 0 : part[tid - 1]);
#pragma unroll
  for (int j = 0; j < 4; j++) {
    int idx = base + j;
    if (idx < n) { offs[idx] = run; cur[idx] = run; run += v[j]; }
  }
  if (b == 0 && tid == 0) offs[n] = ne;
}

__global__ void scatter_kernel(const int* __restrict__ dst, const int* __restrict__ srcIdx,
                               const float2* __restrict__ rel, int* __restrict__ cur,
                               float4* __restrict__ meta, int ne) {
  int e = blockIdx.x * blockDim.x + threadIdx.x;
  if (e < ne) {
    int p = atomicAdd(&cur[dst[e]], 1);
    float2 r = rel[e];
    meta[p] = make_float4(__int_as_float(srcIdx[e]), r.x, r.y, 0.f);
  }
}

// ---------------- weight prep: pack W into MFMA B-fragment layout, bf16 hi/lo ----
// B-frag for v_mfma_f32_16x16x32_bf16 (contiguous-8 convention, matching CDNA3's
// fp8 16x16x32): lane l holds B[k = kt*32 + 8*(l>>4) + e][n = nt*16 + (l&15)].
// nt=8 is the folded attention column: n==128 -> W_att (a_s/a_d dot), rest zero.
// NOTE: if results come back wrong, the alternate mapping is
// k = kt*32 + 16*(e>>2) + 4*(l>>4) + (e&3)  (two 4-chunks) — swap next round.
__global__ void prep_weights(const float* __restrict__ W_emb,
                             const float* __restrict__ W_att,
                             ushort* __restrict__ WBhi, ushort* __restrict__ WBlo) {
  int lane = threadIdx.x;               // 64
  int kt = blockIdx.x / 9, nt = blockIdx.x % 9;
  int part = blockIdx.y, l = blockIdx.z;
  int off = part ? 130 : 0;
  int g = lane >> 4, nn = lane & 15;
  int n = nt * 16 + nn;
  size_t base = (((size_t)((l * 2 + part) * 4 + kt) * 9 + nt) * 64 + lane) * 8;
#pragma unroll
  for (int e = 0; e < 8; e++) {
    int k = kt * 32 + 8 * g + e;
    float val = 0.f;
    if (nt < 8) val = W_emb[(size_t)(l * D + n) * EDGE_IN + off + k];
    else if (nn == 0) val = W_att[(size_t)l * EDGE_IN + off + k];
    ushort hi = f32_to_bf16(val);
    WBhi[base + e] = hi;
    WBlo[base + e] = f32_to_bf16(val - bf16_to_f32(hi));
  }
}

// Wrel: [L][2][128] for the edge kernel
__global__ void rel_prep(const float* __restrict__ W_emb, float* __restrict__ Wrel) {
  int d = threadIdx.x;          // 128
  int c = blockIdx.x;           // 0,1
  int l = blockIdx.y;
  Wrel[(l * 2 + c) * 128 + d] = W_emb[(size_t)(l * D + d) * EDGE_IN + 128 + c];
}

// ---------------- MFMA projections (+ folded attention dots) ----------------
// One block = 16 actors, 128 threads = 2 waves. Wave 0: src matrix -> Ps16+a_s;
// wave 1: dst matrix -> Pd+a_d. fp32 precision recovered via bf16 hi/lo split:
// P = Ahi*Bhi + Alo*Bhi + Ahi*Blo (lo*lo term ~2^-16 rel, negligible).
// R10 post-mortem: fp32 VALU path was issue-bound at 77us (42us VALU issue vs
// 21us FMA floor, invariant across 3 tilings); MFMA removes that floor.
__global__ __launch_bounds__(128) void proj_kernel(
    const float* __restrict__ feat, const ushort* __restrict__ WBhi,
    const ushort* __restrict__ WBlo, __half* __restrict__ Ps16,
    float* __restrict__ Pd, float* __restrict__ a_s, float* __restrict__ a_d,
    int n, int l) {
  __shared__ ushort Ahi[4][64][8];  // [ktile][lane][e]  4 KB
  __shared__ ushort Alo[4][64][8];  // 4 KB
  int i0 = blockIdx.x * 16;
  int tid = threadIdx.x;

  // stage 16 actors x 128 dims: fp32 -> bf16 hi/lo in A-fragment layout.
  // float4 at (m,k4): kk=4*(k4&7)+q -> g=(k4>>1)&3, e=4*(k4&1)+q, lane=m+16g.
  for (int t = tid; t < 512; t += 128) {
    int m = t >> 5;
    int k4 = t & 31;
    int gi = i0 + m;
    float4 v = (gi < n) ? ((const float4*)feat)[(size_t)gi * 32 + k4]
                        : make_float4(0.f, 0.f, 0.f, 0.f);
    int kt = k4 >> 3;
    int lanew = m + 16 * ((k4 >> 1) & 3);
    int eh = (k4 & 1) * 4;
    ushort hx = f32_to_bf16(v.x), hy = f32_to_bf16(v.y);
    ushort hz = f32_to_bf16(v.z), hw = f32_to_bf16(v.w);
    ushort4 h4 = make_ushort4(hx, hy, hz, hw);
    ushort4 l4 = make_ushort4(f32_to_bf16(v.x - bf16_to_f32(hx)),
                              f32_to_bf16(v.y - bf16_to_f32(hy)),
                              f32_to_bf16(v.z - bf16_to_f32(hz)),
                              f32_to_bf16(v.w - bf16_to_f32(hw)));
    *(ushort4*)&Ahi[kt][lanew][eh] = h4;
    *(ushort4*)&Alo[kt][lanew][eh] = l4;
  }
  __syncthreads();

  int w = tid >> 6;      // 0 = src part, 1 = dst part
  int lane = tid & 63;

  bf16x8 ah[4], al[4];
#pragma unroll
  for (int kt = 0; kt < 4; kt++) {
    ah[kt] = *(const bf16x8*)&Ahi[kt][lane][0];
    al[kt] = *(const bf16x8*)&Alo[kt][lane][0];
  }

  const ushort* bh = WBhi + (size_t)(l * 2 + w) * 4 * 9 * 64 * 8;
  const ushort* bl = WBlo + (size_t)(l * 2 + w) * 4 * 9 * 64 * 8;

  f32x4 acc[9];
#pragma unroll
  for (int i = 0; i < 9; i++) acc[i] = (f32x4){0.f, 0.f, 0.f, 0.f};

#pragma unroll
  for (int nt = 0; nt < 9; nt++) {
#pragma unroll
    for (int kt = 0; kt < 4; kt++) {
      size_t idx = (((size_t)kt * 9 + nt) * 64 + lane) * 8;
      bf16x8 bhv = *(const bf16x8*)&bh[idx];
      bf16x8 blv = *(const bf16x8*)&bl[idx];
      acc[nt] = __builtin_amdgcn_mfma_f32_16x16x32_bf16(ah[kt], bhv, acc[nt], 0, 0, 0);
      acc[nt] = __builtin_amdgcn_mfma_f32_16x16x32_bf16(al[kt], bhv, acc[nt], 0, 0, 0);
      acc[nt] = __builtin_amdgcn_mfma_f32_16x16x32_bf16(ah[kt], blv, acc[nt], 0, 0, 0);
    }
  }

  // C/D layout (m89-verified): col = lane&15, row = (lane>>4)*4 + r
  int col0 = lane & 15, rowg = lane >> 4;
  if (w == 0) {
#pragma unroll
    for (int nt = 0; nt < 8; nt++)
#pragma unroll
      for (int r = 0; r < 4; r++) {
        int gi = i0 + rowg * 4 + r;
        if (gi < n) Ps16[(size_t)gi * D + nt * 16 + col0] = __float2half(acc[nt][r]);
      }
    if (col0 == 0) {
#pragma unroll
      for (int r = 0; r < 4; r++) {
        int gi = i0 + rowg * 4 + r;
        if (gi < n) a_s[gi] = acc[8][r];
      }
    }
  } else {
#pragma unroll
    for (int nt = 0; nt < 8; nt++)
#pragma unroll
      for (int r = 0; r < 4; r++) {
        int gi = i0 + rowg * 4 + r;
        if (gi < n) Pd[(size_t)gi * D + nt * 16 + col0] = acc[nt][r];
      }
    if (col0 == 0) {
#pragma unroll
      for (int r = 0; r < 4; r++) {
        int gi = i0 + rowg * 4 + r;
        if (gi < n) a_d[gi] = acc[8][r];
      }
    }
  }
}

// ---------------- edge pass: one wave per dst (unchanged) ----------------
__global__ __launch_bounds__(256) void edge_kernel(
    const __half2* __restrict__ Ps, const float* __restrict__ Pd,
    const float* __restrict__ a_s, const float* __restrict__ a_d,
    const float4* __restrict__ meta, const int* __restrict__ offs,
    const float* __restrict__ Wrel, const float* __restrict__ W_att,
    float* __restrict__ out, int n, int l) {
  int wid = (blockIdx.x * blockDim.x + threadIdx.x) >> 6;
  if (wid >= n) return;
  int lane = threadIdx.x & 63;
  int d0 = 2 * lane;
  const float2 wc0 = *(const float2*)&Wrel[(l * 2 + 0) * 128 + d0];
  const float2 wc1 = *(const float2*)&Wrel[(l * 2 + 1) * 128 + d0];
  float wax = W_att[(size_t)l * EDGE_IN + 128];
  float way = W_att[(size_t)l * EDGE_IN + 129];
  float ad = a_d[wid];
  int p0 = offs[wid], p1 = offs[wid + 1];
  float m = -1e30f, lsum = 0.f;
  float accx = 0.f, accy = 0.f;
  for (int c0 = p0; c0 < p1; c0 += 64) {
    int cn = min(64, p1 - c0);
    int si = 0;
    float rx = 0.f, ry = 0.f, s = -1e30f;
    if (lane < cn) {
      float4 mt = meta[c0 + lane];
      si = __float_as_int(mt.x);
      rx = mt.y;
      ry = mt.z;
      float sc = a_s[si] + ad + rx * wax + ry * way;
      s = (sc > 0.f) ? sc : 0.2f * sc;
    }
    float cm = s;
#pragma unroll
    for (int o = 32; o; o >>= 1) cm = fmaxf(cm, __shfl_xor(cm, o, 64));
    float mnew = fmaxf(m, cm);
    float corrOld = __expf(m - mnew);
    float w = (lane < cn) ? __expf(s - mnew) : 0.f;
    float csum = w;
#pragma unroll
    for (int o = 32; o; o >>= 1) csum += __shfl_xor(csum, o, 64);
    lsum = lsum * corrOld + csum;
    accx *= corrOld;
    accy *= corrOld;
    m = mnew;
    int j = 0;
    for (; j + 8 <= cn; j += 8) {
      float2 f[8];
      float wj[8], xj[8], yj[8];
#pragma unroll
      for (int q = 0; q < 8; q++) {
        int sj = rl_i(si, j + q);
        wj[q] = rl_f(w, j + q);
        xj[q] = rl_f(rx, j + q);
        yj[q] = rl_f(ry, j + q);
        f[q] = __half22float2(Ps[(size_t)sj * 64 + lane]);
      }
#pragma unroll
      for (int q = 0; q < 8; q++) {
        accx += wj[q] * (f[q].x + xj[q] * wc0.x + yj[q] * wc1.x);
        accy += wj[q] * (f[q].y + xj[q] * wc0.y + yj[q] * wc1.y);
      }
    }
    if (j < cn) {
      float2 f[8];
      float wj[8], xj[8], yj[8];
      int r = cn - j;  // 1..7
#pragma unroll
      for (int q = 0; q < 8; q++) {
        if (q < r) {
          int sj = rl_i(si, j + q);
          wj[q] = rl_f(w, j + q);
          xj[q] = rl_f(rx, j + q);
          yj[q] = rl_f(ry, j + q);
          f[q] = __half22float2(Ps[(size_t)sj * 64 + lane]);
        }
      }
#pragma unroll
      for (int q = 0; q < 8; q++) {
        if (q < r) {
          accx += wj[q] * (f[q].x + xj[q] * wc0.x + yj[q] * wc1.x);
          accy += wj[q] * (f[q].y + xj[q] * wc0.y + yj[q] * wc1.y);
        }
      }
    }
  }
  float2 o2 = make_float2(0.f, 0.f);
  if (p1 > p0) {
    float inv = 1.0f / lsum;
    float2 pd = *(const float2*)&Pd[(size_t)wid * D + d0];
    o2.x = fmaxf(accx * inv + pd.x, 0.f);
    o2.y = fmaxf(accy * inv + pd.y, 0.f);
  }
  *(float2*)&out[(size_t)wid * D + d0] = o2;
}

extern "C" void kernel_launch(void* const* d_in, const int* in_sizes, int n_in,
                              void* d_out, int out_size, void* d_ws, size_t ws_size,
                              hipStream_t stream) {
  const float* actor = (const float*)d_in[0];
  const float* rel   = (const float*)d_in[1];
  const float* W_att = (const float*)d_in[2];
  const float* W_emb = (const float*)d_in[3];
  const int* srcIdx  = (const int*)d_in[4];
  const int* dstIdx  = (const int*)d_in[5];
  int n  = in_sizes[0] / D;          // 50000
  int ne = in_sizes[4];              // 800000
  int Lnum = in_sizes[2] / EDGE_IN;  // 2
  float* fout_last = (float*)d_out;

  // workspace carve-up (meta first for 16B alignment)
  float* ws = (float*)d_ws;
  size_t o = 0;
  float4* meta = (float4*)ws; o += 4 * (size_t)ne;
  size_t wbN = (size_t)Lnum * 2 * 4 * 9 * 64 * 8;  // ushorts per buffer
  ushort* WBhi = (ushort*)(ws + o); o += (wbN + 1) / 2;
  ushort* WBlo = (ushort*)(ws + o); o += (wbN + 1) / 2;
  float* Wre = ws + o; o += (size_t)Lnum * 2 * 128;
  float* Pd  = ws + o; o += (size_t)n * D;
  float* a_s = ws + o; o += (size_t)n + 64;
  float* a_d = ws + o; o += (size_t)n + 64;
  __half* Ps16 = (__half*)(ws + o); o += (size_t)n * D / 2;
  int* ibuf = (int*)(ws + o);
  size_t io = 0;
  int* deg  = ibuf + io; io += n + 64;
  int* offs = ibuf + io; io += n + 64;
  int* cur  = ibuf + io; io += n + 64;
  int* bsum = ibuf + io; io += 256;

  int nb = (n + 1023) / 1024;  // chunk-blocks for the scan

  // --- CSR by dst with pre-gathered per-edge metadata ---
  zero_int<<<(n + 255) / 256, 256, 0, stream>>>(deg, n);
  hist_kernel<<<(ne + 255) / 256, 256, 0, stream>>>(dstIdx, deg, ne);
  scan_part<<<nb, 256, 0, stream>>>(deg, bsum, n);
  scan_bsums<<<1, 256, 0, stream>>>(bsum, nb);
  scan_final<<<nb, 256, 0, stream>>>(deg, bsum, offs, cur, n, ne);
  scatter_kernel<<<(ne + 255) / 256, 256, 0, stream>>>(dstIdx, srcIdx, (const float2*)rel,
                                                       cur, meta, ne);
  prep_weights<<<dim3(36, 2, Lnum), 64, 0, stream>>>(W_emb, W_att, WBhi, WBlo);
  rel_prep<<<dim3(2, Lnum), 128, 0, stream>>>(W_emb, Wre);

  // --- layers; d_out doubles as the intermediate feature buffer ---
  const float* fin = actor;
  int nt16 = (n + 15) / 16;
  for (int l = 0; l < Lnum; l++) {
    proj_kernel<<<nt16, 128, 0, stream>>>(fin, WBhi, WBlo, Ps16, Pd, a_s, a_d, n, l);
    edge_kernel<<<(n + 3) / 4, 256, 0, stream>>>((const __half2*)Ps16, Pd, a_s, a_d, meta,
                                                 offs, Wre, W_att, fout_last, n, l);
    fin = fout_last;
  }
}

// Round 12
// 349.032 us; speedup vs baseline: 1.3926x; 1.0532x over previous
//
#include <hip/hip_runtime.h>
#include <hip/hip_fp16.h>

#define D 128
#define EDGE_IN 258

typedef __attribute__((ext_vector_type(8))) short bf16x8;
typedef __attribute__((ext_vector_type(4))) float f32x4;

__device__ __forceinline__ float rl_f(float v, int j) {
  return __int_as_float(__builtin_amdgcn_readlane(__float_as_int(v), j));
}
__device__ __forceinline__ int rl_i(int v, int j) {
  return __builtin_amdgcn_readlane(v, j);
}
__device__ __forceinline__ ushort f32_to_bf16(float f) {
  unsigned u = __float_as_uint(f);
  unsigned r = (u + 0x7FFFu + ((u >> 16) & 1u)) >> 16;  // RNE
  return (ushort)r;
}
__device__ __forceinline__ float bf16_to_f32(ushort h) {
  return __uint_as_float(((unsigned)h) << 16);
}

// ---------------- CSR build ----------------
__global__ void zero_int(int* __restrict__ p, int n) {
  int i = blockIdx.x * blockDim.x + threadIdx.x;
  if (i < n) p[i] = 0;
}

__global__ void hist_kernel(const int* __restrict__ dst, int* __restrict__ deg, int ne) {
  int e = blockIdx.x * blockDim.x + threadIdx.x;
  if (e < ne) atomicAdd(&deg[dst[e]], 1);
}

__global__ __launch_bounds__(256) void scan_part(const int* __restrict__ deg,
                                                 int* __restrict__ bsum, int n) {
  __shared__ int red[256];
  int b = blockIdx.x, tid = threadIdx.x;
  int base = b * 1024 + tid * 4;
  int s = 0;
#pragma unroll
  for (int j = 0; j < 4; j++) { int idx = base + j; if (idx < n) s += deg[idx]; }
  red[tid] = s;
  __syncthreads();
  for (int off = 128; off; off >>= 1) {
    if (tid < off) red[tid] += red[tid + off];
    __syncthreads();
  }
  if (tid == 0) bsum[b] = red[0];
}

__global__ __launch_bounds__(256) void scan_bsums(int* __restrict__ bsum, int nb) {
  __shared__ int part[256];
  int tid = threadIdx.x;
  int v = (tid < nb) ? bsum[tid] : 0;
  part[tid] = v;
  __syncthreads();
  for (int off = 1; off < 256; off <<= 1) {
    int t = (tid >= off) ? part[tid - off] : 0;
    __syncthreads();
    part[tid] += t;
    __syncthreads();
  }
  if (tid < nb) bsum[tid] = (tid == 0) ? 0 : part[tid - 1];  // exclusive
}

__global__ __launch_bounds__(256) void scan_final(const int* __restrict__ deg,
                                                  const int* __restrict__ bsumex,
                                                  int* __restrict__ offs,
                                                  int* __restrict__ cur, int n, int ne) {
  __shared__ int part[256];
  int b = blockIdx.x, tid = threadIdx.x;
  int base = b * 1024 + tid * 4;
  int v[4];
  int s = 0;
#pragma unroll
  for (int j = 0; j < 4; j++) {
    int idx = base + j;
    v[j] = (idx < n) ? deg[idx] : 0;
    s += v[j];
  }
  part[tid] = s;
  __syncthreads();
  for (int off = 1; off < 256; off <<= 1) {
    int t = (tid >= off) ? part[tid - off] : 0;
    __syncthreads();
    part[tid] += t;
    __syncthreads();
  }
  int run = bsumex[b] + ((tid == 0) ? 0 : part[tid - 1]);
#pragma unroll
  for (int j = 0; j < 4; j++) {
    int idx = base + j;
    if (idx < n) { offs[idx] = run; cur[idx] = run; run += v[j]; }
  }
  if (b == 0 && tid == 0) offs[n] = ne;
}

__global__ void scatter_kernel(const int* __restrict__ dst, const int* __restrict__ srcIdx,
                               const float2* __restrict__ rel, int* __restrict__ cur,
                               float4* __restrict__ meta, int ne) {
  int e = blockIdx.x * blockDim.x + threadIdx.x;
  if (e < ne) {
    int p = atomicAdd(&cur[dst[e]], 1);
    float2 r = rel[e];
    meta[p] = make_float4(__int_as_float(srcIdx[e]), r.x, r.y, 0.f);
  }
}

// ---------------- weight prep: pack W into MFMA B-fragment layout, bf16 hi/lo ----
// B-frag for v_mfma_f32_16x16x32_bf16: lane l holds B[k=kt*32+8*(l>>4)+e][n=nt*16+(l&15)].
// nt=8 is the folded attention column (n==128 -> W_att).  Verified R11.
__global__ void prep_weights(const float* __restrict__ W_emb,
                             const float* __restrict__ W_att,
                             ushort* __restrict__ WBhi, ushort* __restrict__ WBlo) {
  int lane = threadIdx.x;               // 64
  int kt = blockIdx.x / 9, nt = blockIdx.x % 9;
  int part = blockIdx.y, l = blockIdx.z;
  int off = part ? 130 : 0;
  int g = lane >> 4, nn = lane & 15;
  int n = nt * 16 + nn;
  size_t base = (((size_t)((l * 2 + part) * 4 + kt) * 9 + nt) * 64 + lane) * 8;
#pragma unroll
  for (int e = 0; e < 8; e++) {
    int k = kt * 32 + 8 * g + e;
    float val = 0.f;
    if (nt < 8) val = W_emb[(size_t)(l * D + n) * EDGE_IN + off + k];
    else if (nn == 0) val = W_att[(size_t)l * EDGE_IN + off + k];
    ushort hi = f32_to_bf16(val);
    WBhi[base + e] = hi;
    WBlo[base + e] = f32_to_bf16(val - bf16_to_f32(hi));
  }
}

// Wrel: [L][2][128] for the edge kernel
__global__ void rel_prep(const float* __restrict__ W_emb, float* __restrict__ Wrel) {
  int d = threadIdx.x;          // 128
  int c = blockIdx.x;           // 0,1
  int l = blockIdx.y;
  Wrel[(l * 2 + c) * 128 + d] = W_emb[(size_t)(l * D + d) * EDGE_IN + 128 + c];
}

// ---------------- MFMA projections (+ folded attention dots) ----------------
// One block = 16 actors, 2 waves: wave 0 -> src (Ps16+a_s), wave 1 -> dst (Pd+a_d).
// fp32 recovered via bf16 hi/lo split: Ahi*Bhi + Alo*Bhi + Ahi*Blo. (R11: verified,
// 77us fp32-VALU proj -> off the top-5; absmax unchanged.)
__global__ __launch_bounds__(128) void proj_kernel(
    const float* __restrict__ feat, const ushort* __restrict__ WBhi,
    const ushort* __restrict__ WBlo, __half* __restrict__ Ps16,
    float* __restrict__ Pd, float* __restrict__ a_s, float* __restrict__ a_d,
    int n, int l) {
  __shared__ ushort Ahi[4][64][8];
  __shared__ ushort Alo[4][64][8];
  int i0 = blockIdx.x * 16;
  int tid = threadIdx.x;

  for (int t = tid; t < 512; t += 128) {
    int m = t >> 5;
    int k4 = t & 31;
    int gi = i0 + m;
    float4 v = (gi < n) ? ((const float4*)feat)[(size_t)gi * 32 + k4]
                        : make_float4(0.f, 0.f, 0.f, 0.f);
    int kt = k4 >> 3;
    int lanew = m + 16 * ((k4 >> 1) & 3);
    int eh = (k4 & 1) * 4;
    ushort hx = f32_to_bf16(v.x), hy = f32_to_bf16(v.y);
    ushort hz = f32_to_bf16(v.z), hw = f32_to_bf16(v.w);
    ushort4 h4 = make_ushort4(hx, hy, hz, hw);
    ushort4 l4 = make_ushort4(f32_to_bf16(v.x - bf16_to_f32(hx)),
                              f32_to_bf16(v.y - bf16_to_f32(hy)),
                              f32_to_bf16(v.z - bf16_to_f32(hz)),
                              f32_to_bf16(v.w - bf16_to_f32(hw)));
    *(ushort4*)&Ahi[kt][lanew][eh] = h4;
    *(ushort4*)&Alo[kt][lanew][eh] = l4;
  }
  __syncthreads();

  int w = tid >> 6;
  int lane = tid & 63;

  bf16x8 ah[4], al[4];
#pragma unroll
  for (int kt = 0; kt < 4; kt++) {
    ah[kt] = *(const bf16x8*)&Ahi[kt][lane][0];
    al[kt] = *(const bf16x8*)&Alo[kt][lane][0];
  }

  const ushort* bh = WBhi + (size_t)(l * 2 + w) * 4 * 9 * 64 * 8;
  const ushort* bl = WBlo + (size_t)(l * 2 + w) * 4 * 9 * 64 * 8;

  f32x4 acc[9];
#pragma unroll
  for (int i = 0; i < 9; i++) acc[i] = (f32x4){0.f, 0.f, 0.f, 0.f};

#pragma unroll
  for (int nt = 0; nt < 9; nt++) {
#pragma unroll
    for (int kt = 0; kt < 4; kt++) {
      size_t idx = (((size_t)kt * 9 + nt) * 64 + lane) * 8;
      bf16x8 bhv = *(const bf16x8*)&bh[idx];
      bf16x8 blv = *(const bf16x8*)&bl[idx];
      acc[nt] = __builtin_amdgcn_mfma_f32_16x16x32_bf16(ah[kt], bhv, acc[nt], 0, 0, 0);
      acc[nt] = __builtin_amdgcn_mfma_f32_16x16x32_bf16(al[kt], bhv, acc[nt], 0, 0, 0);
      acc[nt] = __builtin_amdgcn_mfma_f32_16x16x32_bf16(ah[kt], blv, acc[nt], 0, 0, 0);
    }
  }

  int col0 = lane & 15, rowg = lane >> 4;
  if (w == 0) {
#pragma unroll
    for (int nt = 0; nt < 8; nt++)
#pragma unroll
      for (int r = 0; r < 4; r++) {
        int gi = i0 + rowg * 4 + r;
        if (gi < n) Ps16[(size_t)gi * D + nt * 16 + col0] = __float2half(acc[nt][r]);
      }
    if (col0 == 0) {
#pragma unroll
      for (int r = 0; r < 4; r++) {
        int gi = i0 + rowg * 4 + r;
        if (gi < n) a_s[gi] = acc[8][r];
      }
    }
  } else {
#pragma unroll
    for (int nt = 0; nt < 8; nt++)
#pragma unroll
      for (int r = 0; r < 4; r++) {
        int gi = i0 + rowg * 4 + r;
        if (gi < n) Pd[(size_t)gi * D + nt * 16 + col0] = acc[nt][r];
      }
    if (col0 == 0) {
#pragma unroll
      for (int r = 0; r < 4; r++) {
        int gi = i0 + rowg * 4 + r;
        if (gi < n) a_d[gi] = acc[8][r];
      }
    }
  }
}

// ---------------- edge pass: one wave per dst ----------------
// R12 change: rel contribution factored out of the per-edge loop.
//   sum_e w*(Ps[s]+rx*wc0+ry*wc1) = sum_e w*Ps[s] + Sx*wc0 + Sy*wc1,
//   Sx=sum w*rx, Sy=sum w*ry (wave-reduced in phase A, rescaled like lsum).
// Phase B per edge: 2 readlanes + gather + 2 FMA (was 4 readlanes + 4 FMA).
__global__ __launch_bounds__(256) void edge_kernel(
    const __half2* __restrict__ Ps, const float* __restrict__ Pd,
    const float* __restrict__ a_s, const float* __restrict__ a_d,
    const float4* __restrict__ meta, const int* __restrict__ offs,
    const float* __restrict__ Wrel, const float* __restrict__ W_att,
    float* __restrict__ out, int n, int l) {
  int wid = (blockIdx.x * blockDim.x + threadIdx.x) >> 6;
  if (wid >= n) return;
  int lane = threadIdx.x & 63;
  int d0 = 2 * lane;
  float wax = W_att[(size_t)l * EDGE_IN + 128];
  float way = W_att[(size_t)l * EDGE_IN + 129];
  float ad = a_d[wid];
  int p0 = offs[wid], p1 = offs[wid + 1];
  float m = -1e30f, lsum = 0.f, Sx = 0.f, Sy = 0.f;
  float accx = 0.f, accy = 0.f;
  for (int c0 = p0; c0 < p1; c0 += 64) {
    int cn = min(64, p1 - c0);
    int si = 0;
    float rx = 0.f, ry = 0.f, s = -1e30f;
    if (lane < cn) {
      float4 mt = meta[c0 + lane];
      si = __float_as_int(mt.x);
      rx = mt.y;
      ry = mt.z;
      float sc = a_s[si] + ad + rx * wax + ry * way;
      s = (sc > 0.f) ? sc : 0.2f * sc;
    }
    float cm = s;
#pragma unroll
    for (int o = 32; o; o >>= 1) cm = fmaxf(cm, __shfl_xor(cm, o, 64));
    float mnew = fmaxf(m, cm);
    float corr = __expf(m - mnew);
    float w = (lane < cn) ? __expf(s - mnew) : 0.f;
    float cw = w, cwx = w * rx, cwy = w * ry;
#pragma unroll
    for (int o = 32; o; o >>= 1) {
      cw += __shfl_xor(cw, o, 64);
      cwx += __shfl_xor(cwx, o, 64);
      cwy += __shfl_xor(cwy, o, 64);
    }
    lsum = lsum * corr + cw;
    Sx = Sx * corr + cwx;
    Sy = Sy * corr + cwy;
    accx *= corr;
    accy *= corr;
    m = mnew;
    int j = 0;
    for (; j + 8 <= cn; j += 8) {
      float2 f[8];
      float wj[8];
#pragma unroll
      for (int q = 0; q < 8; q++) {
        int sj = rl_i(si, j + q);
        wj[q] = rl_f(w, j + q);
        f[q] = __half22float2(Ps[(size_t)sj * 64 + lane]);
      }
#pragma unroll
      for (int q = 0; q < 8; q++) {
        accx += wj[q] * f[q].x;
        accy += wj[q] * f[q].y;
      }
    }
    if (j < cn) {
      float2 f[8];
      float wj[8];
      int r = cn - j;  // 1..7
#pragma unroll
      for (int q = 0; q < 8; q++) {
        if (q < r) {
          int sj = rl_i(si, j + q);
          wj[q] = rl_f(w, j + q);
          f[q] = __half22float2(Ps[(size_t)sj * 64 + lane]);
        }
      }
#pragma unroll
      for (int q = 0; q < 8; q++) {
        if (q < r) {
          accx += wj[q] * f[q].x;
          accy += wj[q] * f[q].y;
        }
      }
    }
  }
  float2 o2 = make_float2(0.f, 0.f);
  if (p1 > p0) {
    const float2 wc0 = *(const float2*)&Wrel[(l * 2 + 0) * 128 + d0];
    const float2 wc1 = *(const float2*)&Wrel[(l * 2 + 1) * 128 + d0];
    float inv = 1.0f / lsum;
    float2 pd = *(const float2*)&Pd[(size_t)wid * D + d0];
    accx += Sx * wc0.x + Sy * wc1.x;
    accy += Sx * wc0.y + Sy * wc1.y;
    o2.x = fmaxf(accx * inv + pd.x, 0.f);
    o2.y = fmaxf(accy * inv + pd.y, 0.f);
  }
  *(float2*)&out[(size_t)wid * D + d0] = o2;
}

extern "C" void kernel_launch(void* const* d_in, const int* in_sizes, int n_in,
                              void* d_out, int out_size, void* d_ws, size_t ws_size,
                              hipStream_t stream) {
  const float* actor = (const float*)d_in[0];
  const float* rel   = (const float*)d_in[1];
  const float* W_att = (const float*)d_in[2];
  const float* W_emb = (const float*)d_in[3];
  const int* srcIdx  = (const int*)d_in[4];
  const int* dstIdx  = (const int*)d_in[5];
  int n  = in_sizes[0] / D;          // 50000
  int ne = in_sizes[4];              // 800000
  int Lnum = in_sizes[2] / EDGE_IN;  // 2
  float* fout_last = (float*)d_out;

  float* ws = (float*)d_ws;
  size_t o = 0;
  float4* meta = (float4*)ws; o += 4 * (size_t)ne;
  size_t wbN = (size_t)Lnum * 2 * 4 * 9 * 64 * 8;  // ushorts per buffer
  ushort* WBhi = (ushort*)(ws + o); o += (wbN + 1) / 2;
  ushort* WBlo = (ushort*)(ws + o); o += (wbN + 1) / 2;
  float* Wre = ws + o; o += (size_t)Lnum * 2 * 128;
  float* Pd  = ws + o; o += (size_t)n * D;
  float* a_s = ws + o; o += (size_t)n + 64;
  float* a_d = ws + o; o += (size_t)n + 64;
  __half* Ps16 = (__half*)(ws + o); o += (size_t)n * D / 2;
  int* ibuf = (int*)(ws + o);
  size_t io = 0;
  int* deg  = ibuf + io; io += n + 64;
  int* offs = ibuf + io; io += n + 64;
  int* cur  = ibuf + io; io += n + 64;
  int* bsum = ibuf + io; io += 256;

  int nb = (n + 1023) / 1024;

  zero_int<<<(n + 255) / 256, 256, 0, stream>>>(deg, n);
  hist_kernel<<<(ne + 255) / 256, 256, 0, stream>>>(dstIdx, deg, ne);
  scan_part<<<nb, 256, 0, stream>>>(deg, bsum, n);
  scan_bsums<<<1, 256, 0, stream>>>(bsum, nb);
  scan_final<<<nb, 256, 0, stream>>>(deg, bsum, offs, cur, n, ne);
  scatter_kernel<<<(ne + 255) / 256, 256, 0, stream>>>(dstIdx, srcIdx, (const float2*)rel,
                                                       cur, meta, ne);
  prep_weights<<<dim3(36, 2, Lnum), 64, 0, stream>>>(W_emb, W_att, WBhi, WBlo);
  rel_prep<<<dim3(2, Lnum), 128, 0, stream>>>(W_emb, Wre);

  const float* fin = actor;
  int nt16 = (n + 15) / 16;
  for (int l = 0; l < Lnum; l++) {
    proj_kernel<<<nt16, 128, 0, stream>>>(fin, WBhi, WBlo, Ps16, Pd, a_s, a_d, n, l);
    edge_kernel<<<(n + 3) / 4, 256, 0, stream>>>((const __half2*)Ps16, Pd, a_s, a_d, meta,
                                                 offs, Wre, W_att, fout_last, n, l);
    fin = fout_last;
  }
}